// Round 15
// baseline (257.797 us; speedup 1.0000x reference)
//
#include <hip/hip_runtime.h>
#include <hip/hip_bf16.h>
#include <hip/hip_fp16.h>
#include <cstdint>

#define NH 4
#define HC 128     // H*C
#define INCH 128
#define NEDGE 500000
#define NN 100000

// multisplit geometry
#define KE_SHIFT 11            // 2048 edges per bucket
#define KV_SHIFT 9             // 512 vertices per bucket
#define KE (1 << KE_SHIFT)
#define KV (1 << KV_SHIFT)
#define NBE 245                // ceil(500000/2048)
#define NBV 196                // ceil(100000/512)
#define CAP_E 8192             // mean 6554, +20 sigma
#define CAP_V 10240            // mean 8192, +22 sigma
#define CHUNK_A 8192           // 512 threads x 16 items
#define NB_ABS 64              // absmax role blocks fused into phaseA

typedef float          f32x2 __attribute__((ext_vector_type(2)));
typedef float          f32x4 __attribute__((ext_vector_type(4)));
typedef float          f32x8 __attribute__((ext_vector_type(8)));
typedef unsigned int   u32x2 __attribute__((ext_vector_type(2)));
typedef unsigned int   u32x4 __attribute__((ext_vector_type(4)));
typedef unsigned short u16x8 __attribute__((ext_vector_type(8)));

static __device__ __forceinline__ unsigned short f2bf(float f){
  union { float f; unsigned u; } v; v.f = f;
  unsigned r = v.u + 0x7fffu + ((v.u >> 16) & 1u);
  return (unsigned short)(r >> 16);
}
static __device__ __forceinline__ float bf2f(unsigned short b){
  union { unsigned u; float f; } v; v.u = ((unsigned)b) << 16;
  return v.f;
}
static __device__ __forceinline__ f32x8 bf8f(u16x8 b){
  f32x8 r;
  r[0]=bf2f(b[0]); r[1]=bf2f(b[1]); r[2]=bf2f(b[2]); r[3]=bf2f(b[3]);
  r[4]=bf2f(b[4]); r[5]=bf2f(b[5]); r[6]=bf2f(b[6]); r[7]=bf2f(b[7]);
  return r;
}

// ---- fp8 e4m3fn pack/unpack (HW cvt on gfx950; manual fallback) ----
#if __has_builtin(__builtin_amdgcn_cvt_pk_fp8_f32) && __has_builtin(__builtin_amdgcn_cvt_pk_f32_fp8)
#define FP8_HW 1
#else
#define FP8_HW 0
#endif

#if !FP8_HW
static __device__ __forceinline__ unsigned enc1_fp8(float v){
  union{ __half h; unsigned short u; } c; c.h = __float2half(v);
  unsigned u = c.u;
  unsigned s = (u>>15)&1u, e=(u>>10)&31u, m=u&0x3FFu;
  int e8 = (int)e - 8;
  unsigned lsb = (m>>7)&1u;
  unsigned m8 = (m + 63u + lsb) >> 7;
  if (m8 == 8u){ m8 = 0u; e8 += 1; }
  if (e8 <= 0)  return s<<7;
  if (e8 >= 16) return (s<<7)|0x7Eu;
  return (s<<7)|((unsigned)e8<<3)|m8;
}
static __device__ __forceinline__ float dec1_fp8(unsigned b){
  unsigned s=(b>>7)&1u, e=(b>>3)&15u, m=b&7u;
  union{unsigned u; float f;} r;
  if (e==0u){ r.f = (float)m * 0.001953125f; if(s) r.f = -r.f; }
  else r.u = (s<<31)|((e+120u)<<23)|(m<<20);
  return r.f;
}
#endif

static __device__ __forceinline__ u32x2 pack8_fp8(const f32x8 v){
  u32x2 w;
#if FP8_HW
  int w0 = __builtin_amdgcn_cvt_pk_fp8_f32(v[0], v[1], 0, false);
  w0     = __builtin_amdgcn_cvt_pk_fp8_f32(v[2], v[3], w0, true);
  int w1 = __builtin_amdgcn_cvt_pk_fp8_f32(v[4], v[5], 0, false);
  w1     = __builtin_amdgcn_cvt_pk_fp8_f32(v[6], v[7], w1, true);
  w.x = (unsigned)w0; w.y = (unsigned)w1;
#else
  w.x = enc1_fp8(v[0]) | (enc1_fp8(v[1])<<8) | (enc1_fp8(v[2])<<16) | (enc1_fp8(v[3])<<24);
  w.y = enc1_fp8(v[4]) | (enc1_fp8(v[5])<<8) | (enc1_fp8(v[6])<<16) | (enc1_fp8(v[7])<<24);
#endif
  return w;
}
// acc += c * unpack8(q)
static __device__ __forceinline__ void fma8_fp8(f32x8& acc, float c, u32x2 q){
#if FP8_HW
  f32x2 p;
  p = __builtin_amdgcn_cvt_pk_f32_fp8((int)q.x, false); acc[0] += c*p.x; acc[1] += c*p.y;
  p = __builtin_amdgcn_cvt_pk_f32_fp8((int)q.x, true ); acc[2] += c*p.x; acc[3] += c*p.y;
  p = __builtin_amdgcn_cvt_pk_f32_fp8((int)q.y, false); acc[4] += c*p.x; acc[5] += c*p.y;
  p = __builtin_amdgcn_cvt_pk_f32_fp8((int)q.y, true ); acc[6] += c*p.x; acc[7] += c*p.y;
#else
  acc[0] += c*dec1_fp8(q.x&0xFF);        acc[1] += c*dec1_fp8((q.x>>8)&0xFF);
  acc[2] += c*dec1_fp8((q.x>>16)&0xFF);  acc[3] += c*dec1_fp8(q.x>>24);
  acc[4] += c*dec1_fp8(q.y&0xFF);        acc[5] += c*dec1_fp8((q.y>>8)&0xFF);
  acc[6] += c*dec1_fp8((q.y>>16)&0xFF);  acc[7] += c*dec1_fp8(q.y>>24);
#endif
}

// ---------------- K1: X0bf = bf16(X @ W) (min 2 waves/EU so no spill) ----------------
#define GBM 128
#define GBK 16
__global__ __launch_bounds__(256, 2) void gemm_x0(const float* __restrict__ X,
                                                  const float* __restrict__ Wm,
                                                  unsigned short* __restrict__ X0bf, int nrows){
  __shared__ float As[GBK][GBM+4];
  __shared__ float Bs[GBK][HC+4];
  const int tid  = threadIdx.x;
  const int row0 = blockIdx.x * GBM;
  const int trow = tid >> 4;   // 0..15
  const int tcol = tid & 15;   // 0..15
  float acc[8][8];
  #pragma unroll
  for (int i=0;i<8;i++)
    #pragma unroll
    for (int j=0;j<8;j++) acc[i][j]=0.f;

  for (int k0=0;k0<INCH;k0+=GBK){
    #pragma unroll
    for (int l = tid; l < 512; l += 256){
      int r  = l >> 2;
      int ks = (l & 3) * 4;
      int grow = row0 + r;
      float4 v = make_float4(0.f,0.f,0.f,0.f);
      if (grow < nrows) v = *(const float4*)(X + (size_t)grow*INCH + k0 + ks);
      As[ks+0][r]=v.x; As[ks+1][r]=v.y; As[ks+2][r]=v.z; As[ks+3][r]=v.w;
    }
    #pragma unroll
    for (int l = tid; l < 512; l += 256){
      int r  = l >> 5;
      int cs = (l & 31) * 4;
      float4 v = *(const float4*)(Wm + (size_t)(k0+r)*HC + cs);
      *(float4*)(&Bs[r][cs]) = v;
    }
    __syncthreads();
    #pragma unroll
    for (int kk=0;kk<GBK;kk++){
      float a[8], b[8];
      *(float4*)&a[0] = *(float4*)&As[kk][trow*8];
      *(float4*)&a[4] = *(float4*)&As[kk][trow*8+4];
      *(float4*)&b[0] = *(float4*)&Bs[kk][tcol*8];
      *(float4*)&b[4] = *(float4*)&Bs[kk][tcol*8+4];
      #pragma unroll
      for (int i=0;i<8;i++)
        #pragma unroll
        for (int j=0;j<8;j++) acc[i][j] = fmaf(a[i], b[j], acc[i][j]);
    }
    __syncthreads();
  }
  #pragma unroll
  for (int i=0;i<8;i++){
    int grow = row0 + trow*8 + i;
    if (grow < nrows){
      ushort4 b0, b1;
      b0.x=f2bf(acc[i][0]); b0.y=f2bf(acc[i][1]); b0.z=f2bf(acc[i][2]); b0.w=f2bf(acc[i][3]);
      b1.x=f2bf(acc[i][4]); b1.y=f2bf(acc[i][5]); b1.z=f2bf(acc[i][6]); b1.w=f2bf(acc[i][7]);
      *(ushort4*)(X0bf + (size_t)grow*HC + tcol*8    ) = b0;
      *(ushort4*)(X0bf + (size_t)grow*HC + tcol*8 + 4) = b1;
    }
  }
}

// ---------------- K2: fused {absmax role | phaseA role} (both 512t, low VGPR/LDS) ----------------
__global__ __launch_bounds__(512) void phaseA(const unsigned short* __restrict__ X0bf,
                                              unsigned* __restrict__ gmaxU, int n8,
                                              const int* __restrict__ vertex,
                                              const int* __restrict__ edges, int nnz,
                                              int* __restrict__ cursE, int* __restrict__ cursV,
                                              unsigned* __restrict__ stgE, unsigned* __restrict__ stgV){
  __shared__ int cE[NBE], c2E[NBE], gE[NBE];
  __shared__ int cV[NBV], c2V[NBV], gV[NBV];
  __shared__ float red[8];
  const int t = threadIdx.x;

  if ((int)blockIdx.x < NB_ABS){
    // ---- absmax role: one atomic per block ----
    float pm = 0.f;
    for (int i = blockIdx.x*512 + t; i < n8; i += NB_ABS*512){
      u16x8 v = *(const u16x8*)(X0bf + (size_t)i*8);
      f32x8 f = bf8f(v);
      #pragma unroll
      for (int j=0;j<8;j++) pm = fmaxf(pm, fabsf(f[j]));
    }
    #pragma unroll
    for (int s=1; s<64; s<<=1) pm = fmaxf(pm, __shfl_xor(pm, s, 64));
    const int wid = t >> 6;
    if ((t & 63) == 0) red[wid] = pm;
    __syncthreads();
    if (t == 0){
      float m = red[0];
      #pragma unroll
      for (int j=1;j<8;j++) m = fmaxf(m, red[j]);
      atomicMax(gmaxU, __float_as_uint(m));
    }
    return;
  }

  // ---- phaseA role: LDS-binned multisplit, packed 4B staging ----
  const int base = (blockIdx.x - NB_ABS) * CHUNK_A;
  int ev[16], vv[16];
  #pragma unroll
  for (int j=0;j<16;j++){
    int i = base + t + j*512;
    if (i < nnz){ ev[j] = edges[i]; vv[j] = vertex[i]; }
    else ev[j] = -1;
  }
  for (int j=t;j<NBE;j+=512){ cE[j]=0; c2E[j]=0; }
  for (int j=t;j<NBV;j+=512){ cV[j]=0; c2V[j]=0; }
  __syncthreads();
  #pragma unroll
  for (int j=0;j<16;j++) if (ev[j]>=0){
    atomicAdd(&cE[ev[j]>>KE_SHIFT], 1);
    atomicAdd(&cV[vv[j]>>KV_SHIFT], 1);
  }
  __syncthreads();
  for (int j=t;j<NBE;j+=512) gE[j] = atomicAdd(&cursE[j], cE[j]);
  for (int j=t;j<NBV;j+=512) gV[j] = atomicAdd(&cursV[j], cV[j]);
  __syncthreads();
  #pragma unroll
  for (int j=0;j<16;j++) if (ev[j]>=0){
    int bE = ev[j]>>KE_SHIFT;
    int p = gE[bE] + atomicAdd(&c2E[bE],1);
    if (p < CAP_E) stgE[(size_t)bE*CAP_E + p] = ((unsigned)vv[j] << KE_SHIFT) | (unsigned)(ev[j] & (KE-1));
    int bV = vv[j]>>KV_SHIFT;
    int q = gV[bV] + atomicAdd(&c2V[bV],1);
    if (q < CAP_V) stgV[(size_t)bV*CAP_V + q] = ((unsigned)ev[j] << KV_SHIFT) | (unsigned)(vv[j] & (KV-1));
  }
}

// ---------------- K3: fused phaseB (E-buckets | V-buckets) ----------------
template<int K, int CAP, int IT, int SHIFT, int NB>
__device__ __forceinline__ void phaseB_body(const unsigned* __restrict__ stg,
                                            const int* __restrict__ curs,
                                            int* __restrict__ offsOut,
                                            int* __restrict__ csrOut, int nKeys, int b,
                                            int* cur, int* tsum, int* bsh){
  const int t = threadIdx.x;
  const int k0 = b * K;
  const int kc = min(K, nKeys - k0);
  int c = (t < NB) ? min(curs[t], CAP) : 0;
  bsh[t] = c; __syncthreads();
  for (int d2=1; d2<512; d2<<=1){
    int x = (t>=d2) ? bsh[t-d2] : 0; __syncthreads();
    bsh[t] += x; __syncthreads();
  }
  const int gbase = (b > 0) ? bsh[b-1] : 0;
  const int cnt   = min(curs[b], CAP);
  if (b == NB-1 && t == 0) offsOut[nKeys] = bsh[NB-1];
  unsigned it[IT];
  #pragma unroll
  for (int j=0;j<IT;j++){
    int i = t + j*512;
    it[j] = (i < cnt) ? stg[(size_t)b*CAP + i] : 0xFFFFFFFFu;
  }
  for (int j=t;j<K;j+=512) cur[j] = 0;
  __syncthreads();
  #pragma unroll
  for (int j=0;j<IT;j++) if (it[j] != 0xFFFFFFFFu) atomicAdd(&cur[it[j] & (K-1)], 1);
  __syncthreads();
  constexpr int KPT = K / 512;
  int loc[KPT]; int s = 0;
  #pragma unroll
  for (int j=0;j<KPT;j++){ loc[j] = s; s += cur[t*KPT + j]; }
  tsum[t] = s; __syncthreads();
  for (int d2=1; d2<512; d2<<=1){
    int x = (t>=d2) ? tsum[t-d2] : 0; __syncthreads();
    tsum[t] += x; __syncthreads();
  }
  const int tbase = tsum[t] - s;
  __syncthreads();
  #pragma unroll
  for (int j=0;j<KPT;j++){
    int k = t*KPT + j;
    int abs0 = gbase + tbase + loc[j];
    if (k < kc) offsOut[k0 + k] = abs0;
    cur[k] = abs0;
  }
  __syncthreads();
  #pragma unroll
  for (int j=0;j<IT;j++) if (it[j] != 0xFFFFFFFFu){
    int pos = atomicAdd(&cur[it[j] & (K-1)], 1);
    csrOut[pos] = (int)(it[j] >> SHIFT);
  }
}

__global__ __launch_bounds__(512) void phaseB_fused(const unsigned* __restrict__ stgE,
                                                    const unsigned* __restrict__ stgV,
                                                    const int* __restrict__ cursE,
                                                    const int* __restrict__ cursV,
                                                    int* __restrict__ eoffs, int* __restrict__ voffs,
                                                    int* __restrict__ ecsr, int* __restrict__ vcsr){
  __shared__ int cur[KE];
  __shared__ int tsum[512];
  __shared__ int bsh[512];
  const int b = blockIdx.x;
  if (b < NBE) phaseB_body<KE, CAP_E, CAP_E/512, KE_SHIFT, NBE>(stgE, cursE, eoffs, ecsr, NEDGE, b, cur, tsum, bsh);
  else         phaseB_body<KV, CAP_V, CAP_V/512, KV_SHIFT, NBV>(stgV, cursV, voffs, vcsr, NN, b - NBE, cur, tsum, bsh);
}

// ---------------- K4: per-edge fp8 mean; lane-prefetched indices, predicated unroll-4 ----------------
__global__ __launch_bounds__(256) void edge_agg(const unsigned short* __restrict__ X0bf,
                                                const float* __restrict__ att,
                                                const int* __restrict__ ecsr,
                                                const int* __restrict__ eoffs,
                                                const unsigned* __restrict__ gmaxU,
                                                unsigned char* __restrict__ Xe8,
                                                unsigned* __restrict__ alphaS, int E){
  int eg = blockIdx.x * 16 + (threadIdx.x >> 4);
  if (eg >= E) return;
  const int lane  = threadIdx.x & 15;
  const unsigned cbase = lane * 8;
  const float qs = 448.0f / fmaxf(__uint_as_float(*gmaxU), 1e-20f);
  float attv[8];
  *(f32x4*)&attv[0] = *(const f32x4*)(att + cbase);
  *(f32x4*)&attv[4] = *(const f32x4*)(att + cbase + 4);
  const int start = eoffs[eg];
  const int d     = eoffs[eg+1] - start;
  f32x8 acc0 = {0.f,0.f,0.f,0.f,0.f,0.f,0.f,0.f};
  f32x8 acc1 = {0.f,0.f,0.f,0.f,0.f,0.f,0.f,0.f};
  f32x8 acc2 = {0.f,0.f,0.f,0.f,0.f,0.f,0.f,0.f};
  f32x8 acc3 = {0.f,0.f,0.f,0.f,0.f,0.f,0.f,0.f};
  const u16x8 z8 = {0,0,0,0,0,0,0,0};
  if (d > 0){
    // one coalesced load covers up to 16 member indices; broadcast via shfl
    int myidx = ecsr[start + min(lane, d-1)];
    const int dl = min(d, 16);
    int k = 0;
    for (; k < dl; k += 4){
      int v0 = __shfl(myidx, k, 16);
      int v1 = __shfl(myidx, min(k+1, dl-1), 16);
      int v2 = __shfl(myidx, min(k+2, dl-1), 16);
      int v3 = __shfl(myidx, min(k+3, dl-1), 16);
      u16x8 x0 = *(const u16x8*)(X0bf + (unsigned)v0*(unsigned)HC + cbase);
      u16x8 x1 = *(const u16x8*)(X0bf + (unsigned)v1*(unsigned)HC + cbase);
      u16x8 x2 = *(const u16x8*)(X0bf + (unsigned)v2*(unsigned)HC + cbase);
      u16x8 x3 = *(const u16x8*)(X0bf + (unsigned)v3*(unsigned)HC + cbase);
      x1 = (k+1 < dl) ? x1 : z8;
      x2 = (k+2 < dl) ? x2 : z8;
      x3 = (k+3 < dl) ? x3 : z8;
      acc0 += bf8f(x0);
      acc1 += bf8f(x1);
      acc2 += bf8f(x2);
      acc3 += bf8f(x3);
    }
    for (; k < d; k++){               // rare d>16 tail
      unsigned v0 = (unsigned)ecsr[start + k];
      u16x8 x0 = *(const u16x8*)(X0bf + v0*(unsigned)HC + cbase);
      acc0 += bf8f(x0);
    }
  }
  acc0 = (acc0 + acc1) + (acc2 + acc3);
  const float inv = 1.0f / fmaxf((float)d, 1.0f);
  acc0 *= inv;
  // alpha_h = Xe . att over this head's 32 channels: per-lane dot8, 4-lane reduce
  float p = 0.f;
  #pragma unroll
  for (int j=0;j<8;j++) p = fmaf(acc0[j], attv[j], p);
  p += __shfl_xor(p, 1, 4);
  p += __shfl_xor(p, 2, 4);
  float a = p > 0.f ? p : 0.01f*p;                   // leaky relu
  float e = __expf(a);                               // bounded (|a| <~ 4)
  f32x8 q = acc0 * qs;
  u32x2 w = pack8_fp8(q);
  *(u32x2*)(Xe8 + (unsigned)eg*(unsigned)HC + cbase) = w;
  float e0 = __shfl(e, 0, 16);
  float e1 = __shfl(e, 4, 16);
  float e2 = __shfl(e, 8, 16);
  float e3 = __shfl(e, 12, 16);
  if (lane == 0){
    u32x2 rec;
    rec.x = (unsigned)__half_as_ushort(__float2half(e0)) | ((unsigned)__half_as_ushort(__float2half(e1)) << 16);
    rec.y = (unsigned)__half_as_ushort(__float2half(e2)) | ((unsigned)__half_as_ushort(__float2half(e3)) << 16);
    *(u32x2*)(alphaS + (unsigned)eg*2u) = rec;
  }
}

// ---------------- K5: per-vertex no-max softmax; lane-prefetched vcsr, predicated unroll-4 ----------------
__global__ __launch_bounds__(256) void vert_pass(const unsigned short* __restrict__ X0bf,
                                                 const unsigned char* __restrict__ Xe8,
                                                 const unsigned* __restrict__ alphaS,
                                                 const unsigned* __restrict__ gmaxU,
                                                 const int* __restrict__ vcsr,
                                                 const int* __restrict__ voffs,
                                                 float* __restrict__ out, int N){
  int n = blockIdx.x * 16 + (threadIdx.x >> 4);
  if (n >= N) return;
  const int lane  = threadIdx.x & 15;
  const unsigned cbase = lane * 8;
  const int h     = lane >> 2;   // head for this lane's 8 channels
  const size_t obase = (size_t)n*HC + cbase;
  f32x8 x0 = bf8f(*(const u16x8*)(X0bf + obase));
  const int start = voffs[n];
  const int d     = voffs[n+1] - start;
  if (d == 0){
    f32x4 lo = {x0[0],x0[1],x0[2],x0[3]}, hi = {x0[4],x0[5],x0[6],x0[7]};
    __builtin_nontemporal_store(lo, (f32x4*)(out + obase));
    __builtin_nontemporal_store(hi, (f32x4*)(out + obase + 4));
    return;
  }
  const float dq = fmaxf(__uint_as_float(*gmaxU), 1e-20f) * (1.0f/448.0f);
  const u32x2 z2 = {0,0};

  float den0=0.f, den1=0.f, den2=0.f, den3=0.f;
  f32x8 acc0 = {0.f,0.f,0.f,0.f,0.f,0.f,0.f,0.f};
  f32x8 acc1 = {0.f,0.f,0.f,0.f,0.f,0.f,0.f,0.f};
  f32x8 acc2 = {0.f,0.f,0.f,0.f,0.f,0.f,0.f,0.f};
  f32x8 acc3 = {0.f,0.f,0.f,0.f,0.f,0.f,0.f,0.f};

#define UPD(i, rec, q) { \
    unsigned word_ = (h < 2) ? (rec).x : (rec).y; \
    unsigned h16_  = (h & 1) ? (word_ >> 16) : (word_ & 0xFFFFu); \
    float e_ = __half2float(__ushort_as_half((unsigned short)h16_)); \
    den##i += e_; \
    fma8_fp8(acc##i, e_, (q)); }

  for (int kb = 0; kb < d; kb += 16){
    // one coalesced load covers the next 16 member indices
    int myidx = vcsr[start + min(kb + lane, d-1)];
    const int lim = min(16, d - kb);
    for (int j = 0; j < lim; j += 4){
      unsigned e0 = (unsigned)__shfl(myidx, j, 16);
      unsigned e1 = (unsigned)__shfl(myidx, min(j+1, 15), 16);
      unsigned e2 = (unsigned)__shfl(myidx, min(j+2, 15), 16);
      unsigned e3 = (unsigned)__shfl(myidx, min(j+3, 15), 16);
      u32x2 r0 = *(const u32x2*)(alphaS + e0*2u);
      u32x2 r1 = *(const u32x2*)(alphaS + e1*2u);
      u32x2 r2 = *(const u32x2*)(alphaS + e2*2u);
      u32x2 r3 = *(const u32x2*)(alphaS + e3*2u);
      u32x2 q0 = *(const u32x2*)(Xe8 + e0*(unsigned)HC + cbase);
      u32x2 q1 = *(const u32x2*)(Xe8 + e1*(unsigned)HC + cbase);
      u32x2 q2 = *(const u32x2*)(Xe8 + e2*(unsigned)HC + cbase);
      u32x2 q3 = *(const u32x2*)(Xe8 + e3*(unsigned)HC + cbase);
      r1 = (j+1 < lim) ? r1 : z2;   // zeroed rec -> e_=0 -> no contribution
      r2 = (j+2 < lim) ? r2 : z2;
      r3 = (j+3 < lim) ? r3 : z2;
      UPD(0, r0, q0);
      UPD(1, r1, q1);
      UPD(2, r2, q2);
      UPD(3, r3, q3);
    }
  }
#undef UPD

  float den = (den0 + den1) + (den2 + den3);
  f32x8 acc = (acc0 + acc1) + (acc2 + acc3);
  const float w = dq / (den + 1e-16f);
  acc = acc*w + x0;
  f32x4 lo = {acc[0],acc[1],acc[2],acc[3]};
  f32x4 hi = {acc[4],acc[5],acc[6],acc[7]};
  __builtin_nontemporal_store(lo, (f32x4*)(out + obase));
  __builtin_nontemporal_store(hi, (f32x4*)(out + obase + 4));
}

extern "C" void kernel_launch(void* const* d_in, const int* in_sizes, int n_in,
                              void* d_out, int out_size, void* d_ws, size_t ws_size,
                              hipStream_t stream){
  const float* X   = (const float*)d_in[0];
  const float* Wm  = (const float*)d_in[1];
  const float* att = (const float*)d_in[2];
  const int* vertex = (const int*)d_in[3];
  const int* edges  = (const int*)d_in[4];
  const int N   = in_sizes[0] / INCH;
  const int NNZ = in_sizes[3];
  const int E   = NEDGE;

  char* ws = (char*)d_ws;
  size_t off = 0;
  auto alloc = [&](size_t bytes)->char*{
    char* p = ws + off;
    off += (bytes + 255) & ~(size_t)255;
    return p;
  };
  unsigned char*  Xe8    = (unsigned char*)alloc((size_t)E * HC);                            // 64 MB
  unsigned short* X0bf   = (unsigned short*)alloc((size_t)NN * HC * sizeof(unsigned short)); // 25.6 MB
  unsigned*       alphaS = (unsigned*)alloc((size_t)E * 2 * sizeof(unsigned));               // 4 MB
  int*            eoffs  = (int*)alloc((size_t)(E+1) * sizeof(int));
  int*            voffs  = (int*)alloc((size_t)(NN+1) * sizeof(int));
  int*            ecsr   = (int*)alloc((size_t)NNZ * sizeof(int));
  int*            vcsr   = (int*)alloc((size_t)NNZ * sizeof(int));
  int*            curs   = (int*)alloc((size_t)(NBE + NBV + 1) * sizeof(int));
  int*            cursE  = curs;
  int*            cursV  = curs + NBE;
  unsigned*       gmaxU  = (unsigned*)(curs + NBE + NBV);
  // packed staging aliases Xe8 (16 MB < 64 MB; dead once edge_agg runs)
  unsigned* stgE = (unsigned*)(void*)Xe8;
  unsigned* stgV = (unsigned*)((char*)(void*)Xe8 + (size_t)NBE * CAP_E * sizeof(unsigned));

  const int nA = (NNZ + CHUNK_A - 1) / CHUNK_A;

  hipMemsetAsync(curs, 0, (size_t)(NBE + NBV + 1) * sizeof(int), stream);
  gemm_x0<<<(N + GBM - 1)/GBM, 256, 0, stream>>>(X, Wm, X0bf, N);
  phaseA<<<NB_ABS + nA, 512, 0, stream>>>(X0bf, gmaxU, N * HC / 8,
                                          vertex, edges, NNZ, cursE, cursV, stgE, stgV);
  phaseB_fused<<<NBE + NBV, 512, 0, stream>>>(stgE, stgV, cursE, cursV, eoffs, voffs, ecsr, vcsr);
  edge_agg<<<(E + 15)/16, 256, 0, stream>>>(X0bf, att, ecsr, eoffs, gmaxU, Xe8, alphaS, E);
  vert_pass<<<(N + 15)/16, 256, 0, stream>>>(X0bf, Xe8, alphaS, gmaxU, vcsr, voffs, (float*)d_out, N);
}

// Round 16
// 249.524 us; speedup vs baseline: 1.0332x; 1.0332x over previous
//
#include <hip/hip_runtime.h>
#include <hip/hip_bf16.h>
#include <hip/hip_fp16.h>
#include <cstdint>

#define NH 4
#define HC 128     // H*C
#define INCH 128
#define NEDGE 500000
#define NN 100000

// multisplit geometry
#define KE_SHIFT 11            // 2048 edges per bucket
#define KV_SHIFT 9             // 512 vertices per bucket
#define KE (1 << KE_SHIFT)
#define KV (1 << KV_SHIFT)
#define NBE 245                // ceil(500000/2048)
#define NBV 196                // ceil(100000/512)
#define CAP_E 8192             // mean 6554, +20 sigma
#define CAP_V 10240            // mean 8192, +22 sigma
#define CHUNK_A 8192           // 512 threads x 16 items
#define NB_ABS 64              // absmax role blocks fused into phaseA

typedef float          f32x2 __attribute__((ext_vector_type(2)));
typedef float          f32x4 __attribute__((ext_vector_type(4)));
typedef float          f32x8 __attribute__((ext_vector_type(8)));
typedef unsigned int   u32x2 __attribute__((ext_vector_type(2)));
typedef unsigned int   u32x4 __attribute__((ext_vector_type(4)));
typedef unsigned short u16x8 __attribute__((ext_vector_type(8)));

static __device__ __forceinline__ unsigned short f2bf(float f){
  union { float f; unsigned u; } v; v.f = f;
  unsigned r = v.u + 0x7fffu + ((v.u >> 16) & 1u);
  return (unsigned short)(r >> 16);
}
static __device__ __forceinline__ float bf2f(unsigned short b){
  union { unsigned u; float f; } v; v.u = ((unsigned)b) << 16;
  return v.f;
}
static __device__ __forceinline__ f32x8 bf8f(u16x8 b){
  f32x8 r;
  r[0]=bf2f(b[0]); r[1]=bf2f(b[1]); r[2]=bf2f(b[2]); r[3]=bf2f(b[3]);
  r[4]=bf2f(b[4]); r[5]=bf2f(b[5]); r[6]=bf2f(b[6]); r[7]=bf2f(b[7]);
  return r;
}

// ---- fp8 e4m3fn pack/unpack (HW cvt on gfx950; manual fallback) ----
#if __has_builtin(__builtin_amdgcn_cvt_pk_fp8_f32) && __has_builtin(__builtin_amdgcn_cvt_pk_f32_fp8)
#define FP8_HW 1
#else
#define FP8_HW 0
#endif

#if !FP8_HW
static __device__ __forceinline__ unsigned enc1_fp8(float v){
  union{ __half h; unsigned short u; } c; c.h = __float2half(v);
  unsigned u = c.u;
  unsigned s = (u>>15)&1u, e=(u>>10)&31u, m=u&0x3FFu;
  int e8 = (int)e - 8;
  unsigned lsb = (m>>7)&1u;
  unsigned m8 = (m + 63u + lsb) >> 7;
  if (m8 == 8u){ m8 = 0u; e8 += 1; }
  if (e8 <= 0)  return s<<7;
  if (e8 >= 16) return (s<<7)|0x7Eu;
  return (s<<7)|((unsigned)e8<<3)|m8;
}
static __device__ __forceinline__ float dec1_fp8(unsigned b){
  unsigned s=(b>>7)&1u, e=(b>>3)&15u, m=b&7u;
  union{unsigned u; float f;} r;
  if (e==0u){ r.f = (float)m * 0.001953125f; if(s) r.f = -r.f; }
  else r.u = (s<<31)|((e+120u)<<23)|(m<<20);
  return r.f;
}
#endif

static __device__ __forceinline__ u32x2 pack8_fp8(const f32x8 v){
  u32x2 w;
#if FP8_HW
  int w0 = __builtin_amdgcn_cvt_pk_fp8_f32(v[0], v[1], 0, false);
  w0     = __builtin_amdgcn_cvt_pk_fp8_f32(v[2], v[3], w0, true);
  int w1 = __builtin_amdgcn_cvt_pk_fp8_f32(v[4], v[5], 0, false);
  w1     = __builtin_amdgcn_cvt_pk_fp8_f32(v[6], v[7], w1, true);
  w.x = (unsigned)w0; w.y = (unsigned)w1;
#else
  w.x = enc1_fp8(v[0]) | (enc1_fp8(v[1])<<8) | (enc1_fp8(v[2])<<16) | (enc1_fp8(v[3])<<24);
  w.y = enc1_fp8(v[4]) | (enc1_fp8(v[5])<<8) | (enc1_fp8(v[6])<<16) | (enc1_fp8(v[7])<<24);
#endif
  return w;
}
// acc += c * unpack8(q)
static __device__ __forceinline__ void fma8_fp8(f32x8& acc, float c, u32x2 q){
#if FP8_HW
  f32x2 p;
  p = __builtin_amdgcn_cvt_pk_f32_fp8((int)q.x, false); acc[0] += c*p.x; acc[1] += c*p.y;
  p = __builtin_amdgcn_cvt_pk_f32_fp8((int)q.x, true ); acc[2] += c*p.x; acc[3] += c*p.y;
  p = __builtin_amdgcn_cvt_pk_f32_fp8((int)q.y, false); acc[4] += c*p.x; acc[5] += c*p.y;
  p = __builtin_amdgcn_cvt_pk_f32_fp8((int)q.y, true ); acc[6] += c*p.x; acc[7] += c*p.y;
#else
  acc[0] += c*dec1_fp8(q.x&0xFF);        acc[1] += c*dec1_fp8((q.x>>8)&0xFF);
  acc[2] += c*dec1_fp8((q.x>>16)&0xFF);  acc[3] += c*dec1_fp8(q.x>>24);
  acc[4] += c*dec1_fp8(q.y&0xFF);        acc[5] += c*dec1_fp8((q.y>>8)&0xFF);
  acc[6] += c*dec1_fp8((q.y>>16)&0xFF);  acc[7] += c*dec1_fp8(q.y>>24);
#endif
}

// ---------------- K1: X0bf = bf16(X @ W) (min 2 waves/EU so no spill) ----------------
#define GBM 128
#define GBK 16
__global__ __launch_bounds__(256, 2) void gemm_x0(const float* __restrict__ X,
                                                  const float* __restrict__ Wm,
                                                  unsigned short* __restrict__ X0bf, int nrows){
  __shared__ float As[GBK][GBM+4];
  __shared__ float Bs[GBK][HC+4];
  const int tid  = threadIdx.x;
  const int row0 = blockIdx.x * GBM;
  const int trow = tid >> 4;   // 0..15
  const int tcol = tid & 15;   // 0..15
  float acc[8][8];
  #pragma unroll
  for (int i=0;i<8;i++)
    #pragma unroll
    for (int j=0;j<8;j++) acc[i][j]=0.f;

  for (int k0=0;k0<INCH;k0+=GBK){
    #pragma unroll
    for (int l = tid; l < 512; l += 256){
      int r  = l >> 2;
      int ks = (l & 3) * 4;
      int grow = row0 + r;
      float4 v = make_float4(0.f,0.f,0.f,0.f);
      if (grow < nrows) v = *(const float4*)(X + (size_t)grow*INCH + k0 + ks);
      As[ks+0][r]=v.x; As[ks+1][r]=v.y; As[ks+2][r]=v.z; As[ks+3][r]=v.w;
    }
    #pragma unroll
    for (int l = tid; l < 512; l += 256){
      int r  = l >> 5;
      int cs = (l & 31) * 4;
      float4 v = *(const float4*)(Wm + (size_t)(k0+r)*HC + cs);
      *(float4*)(&Bs[r][cs]) = v;
    }
    __syncthreads();
    #pragma unroll
    for (int kk=0;kk<GBK;kk++){
      float a[8], b[8];
      *(float4*)&a[0] = *(float4*)&As[kk][trow*8];
      *(float4*)&a[4] = *(float4*)&As[kk][trow*8+4];
      *(float4*)&b[0] = *(float4*)&Bs[kk][tcol*8];
      *(float4*)&b[4] = *(float4*)&Bs[kk][tcol*8+4];
      #pragma unroll
      for (int i=0;i<8;i++)
        #pragma unroll
        for (int j=0;j<8;j++) acc[i][j] = fmaf(a[i], b[j], acc[i][j]);
    }
    __syncthreads();
  }
  #pragma unroll
  for (int i=0;i<8;i++){
    int grow = row0 + trow*8 + i;
    if (grow < nrows){
      ushort4 b0, b1;
      b0.x=f2bf(acc[i][0]); b0.y=f2bf(acc[i][1]); b0.z=f2bf(acc[i][2]); b0.w=f2bf(acc[i][3]);
      b1.x=f2bf(acc[i][4]); b1.y=f2bf(acc[i][5]); b1.z=f2bf(acc[i][6]); b1.w=f2bf(acc[i][7]);
      *(ushort4*)(X0bf + (size_t)grow*HC + tcol*8    ) = b0;
      *(ushort4*)(X0bf + (size_t)grow*HC + tcol*8 + 4) = b1;
    }
  }
}

// ---------------- K2: fused {absmax role | phaseA role} (both 512t, low VGPR/LDS) ----------------
__global__ __launch_bounds__(512) void phaseA(const unsigned short* __restrict__ X0bf,
                                              unsigned* __restrict__ gmaxU, int n8,
                                              const int* __restrict__ vertex,
                                              const int* __restrict__ edges, int nnz,
                                              int* __restrict__ cursE, int* __restrict__ cursV,
                                              unsigned* __restrict__ stgE, unsigned* __restrict__ stgV){
  __shared__ int cE[NBE], c2E[NBE], gE[NBE];
  __shared__ int cV[NBV], c2V[NBV], gV[NBV];
  __shared__ float red[8];
  const int t = threadIdx.x;

  if ((int)blockIdx.x < NB_ABS){
    // ---- absmax role: one atomic per block ----
    float pm = 0.f;
    for (int i = blockIdx.x*512 + t; i < n8; i += NB_ABS*512){
      u16x8 v = *(const u16x8*)(X0bf + (size_t)i*8);
      f32x8 f = bf8f(v);
      #pragma unroll
      for (int j=0;j<8;j++) pm = fmaxf(pm, fabsf(f[j]));
    }
    #pragma unroll
    for (int s=1; s<64; s<<=1) pm = fmaxf(pm, __shfl_xor(pm, s, 64));
    const int wid = t >> 6;
    if ((t & 63) == 0) red[wid] = pm;
    __syncthreads();
    if (t == 0){
      float m = red[0];
      #pragma unroll
      for (int j=1;j<8;j++) m = fmaxf(m, red[j]);
      atomicMax(gmaxU, __float_as_uint(m));
    }
    return;
  }

  // ---- phaseA role: LDS-binned multisplit, packed 4B staging ----
  const int base = (blockIdx.x - NB_ABS) * CHUNK_A;
  int ev[16], vv[16];
  #pragma unroll
  for (int j=0;j<16;j++){
    int i = base + t + j*512;
    if (i < nnz){ ev[j] = edges[i]; vv[j] = vertex[i]; }
    else ev[j] = -1;
  }
  for (int j=t;j<NBE;j+=512){ cE[j]=0; c2E[j]=0; }
  for (int j=t;j<NBV;j+=512){ cV[j]=0; c2V[j]=0; }
  __syncthreads();
  #pragma unroll
  for (int j=0;j<16;j++) if (ev[j]>=0){
    atomicAdd(&cE[ev[j]>>KE_SHIFT], 1);
    atomicAdd(&cV[vv[j]>>KV_SHIFT], 1);
  }
  __syncthreads();
  for (int j=t;j<NBE;j+=512) gE[j] = atomicAdd(&cursE[j], cE[j]);
  for (int j=t;j<NBV;j+=512) gV[j] = atomicAdd(&cursV[j], cV[j]);
  __syncthreads();
  #pragma unroll
  for (int j=0;j<16;j++) if (ev[j]>=0){
    int bE = ev[j]>>KE_SHIFT;
    int p = gE[bE] + atomicAdd(&c2E[bE],1);
    if (p < CAP_E) stgE[(size_t)bE*CAP_E + p] = ((unsigned)vv[j] << KE_SHIFT) | (unsigned)(ev[j] & (KE-1));
    int bV = vv[j]>>KV_SHIFT;
    int q = gV[bV] + atomicAdd(&c2V[bV],1);
    if (q < CAP_V) stgV[(size_t)bV*CAP_V + q] = ((unsigned)ev[j] << KV_SHIFT) | (unsigned)(vv[j] & (KV-1));
  }
}

// ---------------- K3: fused phaseB (E-buckets | V-buckets) ----------------
template<int K, int CAP, int IT, int SHIFT, int NB>
__device__ __forceinline__ void phaseB_body(const unsigned* __restrict__ stg,
                                            const int* __restrict__ curs,
                                            int* __restrict__ offsOut,
                                            int* __restrict__ csrOut, int nKeys, int b,
                                            int* cur, int* tsum, int* bsh){
  const int t = threadIdx.x;
  const int k0 = b * K;
  const int kc = min(K, nKeys - k0);
  int c = (t < NB) ? min(curs[t], CAP) : 0;
  bsh[t] = c; __syncthreads();
  for (int d2=1; d2<512; d2<<=1){
    int x = (t>=d2) ? bsh[t-d2] : 0; __syncthreads();
    bsh[t] += x; __syncthreads();
  }
  const int gbase = (b > 0) ? bsh[b-1] : 0;
  const int cnt   = min(curs[b], CAP);
  if (b == NB-1 && t == 0) offsOut[nKeys] = bsh[NB-1];
  unsigned it[IT];
  #pragma unroll
  for (int j=0;j<IT;j++){
    int i = t + j*512;
    it[j] = (i < cnt) ? stg[(size_t)b*CAP + i] : 0xFFFFFFFFu;
  }
  for (int j=t;j<K;j+=512) cur[j] = 0;
  __syncthreads();
  #pragma unroll
  for (int j=0;j<IT;j++) if (it[j] != 0xFFFFFFFFu) atomicAdd(&cur[it[j] & (K-1)], 1);
  __syncthreads();
  constexpr int KPT = K / 512;
  int loc[KPT]; int s = 0;
  #pragma unroll
  for (int j=0;j<KPT;j++){ loc[j] = s; s += cur[t*KPT + j]; }
  tsum[t] = s; __syncthreads();
  for (int d2=1; d2<512; d2<<=1){
    int x = (t>=d2) ? tsum[t-d2] : 0; __syncthreads();
    tsum[t] += x; __syncthreads();
  }
  const int tbase = tsum[t] - s;
  __syncthreads();
  #pragma unroll
  for (int j=0;j<KPT;j++){
    int k = t*KPT + j;
    int abs0 = gbase + tbase + loc[j];
    if (k < kc) offsOut[k0 + k] = abs0;
    cur[k] = abs0;
  }
  __syncthreads();
  #pragma unroll
  for (int j=0;j<IT;j++) if (it[j] != 0xFFFFFFFFu){
    int pos = atomicAdd(&cur[it[j] & (K-1)], 1);
    csrOut[pos] = (int)(it[j] >> SHIFT);
  }
}

__global__ __launch_bounds__(512) void phaseB_fused(const unsigned* __restrict__ stgE,
                                                    const unsigned* __restrict__ stgV,
                                                    const int* __restrict__ cursE,
                                                    const int* __restrict__ cursV,
                                                    int* __restrict__ eoffs, int* __restrict__ voffs,
                                                    int* __restrict__ ecsr, int* __restrict__ vcsr){
  __shared__ int cur[KE];
  __shared__ int tsum[512];
  __shared__ int bsh[512];
  const int b = blockIdx.x;
  if (b < NBE) phaseB_body<KE, CAP_E, CAP_E/512, KE_SHIFT, NBE>(stgE, cursE, eoffs, ecsr, NEDGE, b, cur, tsum, bsh);
  else         phaseB_body<KV, CAP_V, CAP_V/512, KV_SHIFT, NBV>(stgV, cursV, voffs, vcsr, NN, b - NBE, cur, tsum, bsh);
}

// ---------------- K4: per-edge fp8 mean (round-14 body: unroll-2, 28 VGPR) ----------------
__global__ __launch_bounds__(256) void edge_agg(const unsigned short* __restrict__ X0bf,
                                                const float* __restrict__ att,
                                                const int* __restrict__ ecsr,
                                                const int* __restrict__ eoffs,
                                                const unsigned* __restrict__ gmaxU,
                                                unsigned char* __restrict__ Xe8,
                                                unsigned* __restrict__ alphaS, int E){
  int eg = blockIdx.x * 16 + (threadIdx.x >> 4);
  if (eg >= E) return;
  const int lane  = threadIdx.x & 15;
  const unsigned cbase = lane * 8;
  const float qs = 448.0f / fmaxf(__uint_as_float(*gmaxU), 1e-20f);
  float attv[8];
  *(f32x4*)&attv[0] = *(const f32x4*)(att + cbase);
  *(f32x4*)&attv[4] = *(const f32x4*)(att + cbase + 4);
  const int start = eoffs[eg];
  const int d     = eoffs[eg+1] - start;
  f32x8 acc0 = {0.f,0.f,0.f,0.f,0.f,0.f,0.f,0.f};
  f32x8 acc1 = {0.f,0.f,0.f,0.f,0.f,0.f,0.f,0.f};
  int k = 0;
  for (; k+1<d; k+=2){
    unsigned v0 = (unsigned)ecsr[start + k];
    unsigned v1 = (unsigned)ecsr[start + k + 1];
    u16x8 x0 = *(const u16x8*)(X0bf + v0*(unsigned)HC + cbase);
    u16x8 x1 = *(const u16x8*)(X0bf + v1*(unsigned)HC + cbase);
    acc0 += bf8f(x0);
    acc1 += bf8f(x1);
  }
  if (k < d){
    unsigned v0 = (unsigned)ecsr[start + k];
    u16x8 x0 = *(const u16x8*)(X0bf + v0*(unsigned)HC + cbase);
    acc0 += bf8f(x0);
  }
  acc0 += acc1;
  const float inv = 1.0f / fmaxf((float)d, 1.0f);
  acc0 *= inv;
  // alpha_h = Xe . att over this head's 32 channels: per-lane dot8, 4-lane reduce
  float p = 0.f;
  #pragma unroll
  for (int j=0;j<8;j++) p = fmaf(acc0[j], attv[j], p);
  p += __shfl_xor(p, 1, 4);
  p += __shfl_xor(p, 2, 4);
  float a = p > 0.f ? p : 0.01f*p;                   // leaky relu
  float e = __expf(a);                               // bounded (|a| <~ 4)
  f32x8 q = acc0 * qs;
  u32x2 w = pack8_fp8(q);
  *(u32x2*)(Xe8 + (unsigned)eg*(unsigned)HC + cbase) = w;
  float e0 = __shfl(e, 0, 16);
  float e1 = __shfl(e, 4, 16);
  float e2 = __shfl(e, 8, 16);
  float e3 = __shfl(e, 12, 16);
  if (lane == 0){
    u32x2 rec;
    rec.x = (unsigned)__half_as_ushort(__float2half(e0)) | ((unsigned)__half_as_ushort(__float2half(e1)) << 16);
    rec.y = (unsigned)__half_as_ushort(__float2half(e2)) | ((unsigned)__half_as_ushort(__float2half(e3)) << 16);
    *(u32x2*)(alphaS + (unsigned)eg*2u) = rec;
  }
}

// ---------------- K5: per-vertex no-max softmax; lane-prefetched vcsr, predicated unroll-4 ----------------
__global__ __launch_bounds__(256) void vert_pass(const unsigned short* __restrict__ X0bf,
                                                 const unsigned char* __restrict__ Xe8,
                                                 const unsigned* __restrict__ alphaS,
                                                 const unsigned* __restrict__ gmaxU,
                                                 const int* __restrict__ vcsr,
                                                 const int* __restrict__ voffs,
                                                 float* __restrict__ out, int N){
  int n = blockIdx.x * 16 + (threadIdx.x >> 4);
  if (n >= N) return;
  const int lane  = threadIdx.x & 15;
  const unsigned cbase = lane * 8;
  const int h     = lane >> 2;   // head for this lane's 8 channels
  const size_t obase = (size_t)n*HC + cbase;
  f32x8 x0 = bf8f(*(const u16x8*)(X0bf + obase));
  const int start = voffs[n];
  const int d     = voffs[n+1] - start;
  if (d == 0){
    f32x4 lo = {x0[0],x0[1],x0[2],x0[3]}, hi = {x0[4],x0[5],x0[6],x0[7]};
    __builtin_nontemporal_store(lo, (f32x4*)(out + obase));
    __builtin_nontemporal_store(hi, (f32x4*)(out + obase + 4));
    return;
  }
  const float dq = fmaxf(__uint_as_float(*gmaxU), 1e-20f) * (1.0f/448.0f);
  const u32x2 z2 = {0,0};

  float den0=0.f, den1=0.f, den2=0.f, den3=0.f;
  f32x8 acc0 = {0.f,0.f,0.f,0.f,0.f,0.f,0.f,0.f};
  f32x8 acc1 = {0.f,0.f,0.f,0.f,0.f,0.f,0.f,0.f};
  f32x8 acc2 = {0.f,0.f,0.f,0.f,0.f,0.f,0.f,0.f};
  f32x8 acc3 = {0.f,0.f,0.f,0.f,0.f,0.f,0.f,0.f};

#define UPD(i, rec, q) { \
    unsigned word_ = (h < 2) ? (rec).x : (rec).y; \
    unsigned h16_  = (h & 1) ? (word_ >> 16) : (word_ & 0xFFFFu); \
    float e_ = __half2float(__ushort_as_half((unsigned short)h16_)); \
    den##i += e_; \
    fma8_fp8(acc##i, e_, (q)); }

  for (int kb = 0; kb < d; kb += 16){
    // one coalesced load covers the next 16 member indices
    int myidx = vcsr[start + min(kb + lane, d-1)];
    const int lim = min(16, d - kb);
    for (int j = 0; j < lim; j += 4){
      unsigned e0 = (unsigned)__shfl(myidx, j, 16);
      unsigned e1 = (unsigned)__shfl(myidx, min(j+1, 15), 16);
      unsigned e2 = (unsigned)__shfl(myidx, min(j+2, 15), 16);
      unsigned e3 = (unsigned)__shfl(myidx, min(j+3, 15), 16);
      u32x2 r0 = *(const u32x2*)(alphaS + e0*2u);
      u32x2 r1 = *(const u32x2*)(alphaS + e1*2u);
      u32x2 r2 = *(const u32x2*)(alphaS + e2*2u);
      u32x2 r3 = *(const u32x2*)(alphaS + e3*2u);
      u32x2 q0 = *(const u32x2*)(Xe8 + e0*(unsigned)HC + cbase);
      u32x2 q1 = *(const u32x2*)(Xe8 + e1*(unsigned)HC + cbase);
      u32x2 q2 = *(const u32x2*)(Xe8 + e2*(unsigned)HC + cbase);
      u32x2 q3 = *(const u32x2*)(Xe8 + e3*(unsigned)HC + cbase);
      r1 = (j+1 < lim) ? r1 : z2;   // zeroed rec -> e_=0 -> no contribution
      r2 = (j+2 < lim) ? r2 : z2;
      r3 = (j+3 < lim) ? r3 : z2;
      UPD(0, r0, q0);
      UPD(1, r1, q1);
      UPD(2, r2, q2);
      UPD(3, r3, q3);
    }
  }
#undef UPD

  float den = (den0 + den1) + (den2 + den3);
  f32x8 acc = (acc0 + acc1) + (acc2 + acc3);
  const float w = dq / (den + 1e-16f);
  acc = acc*w + x0;
  f32x4 lo = {acc[0],acc[1],acc[2],acc[3]};
  f32x4 hi = {acc[4],acc[5],acc[6],acc[7]};
  __builtin_nontemporal_store(lo, (f32x4*)(out + obase));
  __builtin_nontemporal_store(hi, (f32x4*)(out + obase + 4));
}

extern "C" void kernel_launch(void* const* d_in, const int* in_sizes, int n_in,
                              void* d_out, int out_size, void* d_ws, size_t ws_size,
                              hipStream_t stream){
  const float* X   = (const float*)d_in[0];
  const float* Wm  = (const float*)d_in[1];
  const float* att = (const float*)d_in[2];
  const int* vertex = (const int*)d_in[3];
  const int* edges  = (const int*)d_in[4];
  const int N   = in_sizes[0] / INCH;
  const int NNZ = in_sizes[3];
  const int E   = NEDGE;

  char* ws = (char*)d_ws;
  size_t off = 0;
  auto alloc = [&](size_t bytes)->char*{
    char* p = ws + off;
    off += (bytes + 255) & ~(size_t)255;
    return p;
  };
  unsigned char*  Xe8    = (unsigned char*)alloc((size_t)E * HC);                            // 64 MB
  unsigned short* X0bf   = (unsigned short*)alloc((size_t)NN * HC * sizeof(unsigned short)); // 25.6 MB
  unsigned*       alphaS = (unsigned*)alloc((size_t)E * 2 * sizeof(unsigned));               // 4 MB
  int*            eoffs  = (int*)alloc((size_t)(E+1) * sizeof(int));
  int*            voffs  = (int*)alloc((size_t)(NN+1) * sizeof(int));
  int*            ecsr   = (int*)alloc((size_t)NNZ * sizeof(int));
  int*            vcsr   = (int*)alloc((size_t)NNZ * sizeof(int));
  int*            curs   = (int*)alloc((size_t)(NBE + NBV + 1) * sizeof(int));
  int*            cursE  = curs;
  int*            cursV  = curs + NBE;
  unsigned*       gmaxU  = (unsigned*)(curs + NBE + NBV);
  // packed staging aliases Xe8 (16 MB < 64 MB; dead once edge_agg runs)
  unsigned* stgE = (unsigned*)(void*)Xe8;
  unsigned* stgV = (unsigned*)((char*)(void*)Xe8 + (size_t)NBE * CAP_E * sizeof(unsigned));

  const int nA = (NNZ + CHUNK_A - 1) / CHUNK_A;

  hipMemsetAsync(curs, 0, (size_t)(NBE + NBV + 1) * sizeof(int), stream);
  gemm_x0<<<(N + GBM - 1)/GBM, 256, 0, stream>>>(X, Wm, X0bf, N);
  phaseA<<<NB_ABS + nA, 512, 0, stream>>>(X0bf, gmaxU, N * HC / 8,
                                          vertex, edges, NNZ, cursE, cursV, stgE, stgV);
  phaseB_fused<<<NBE + NBV, 512, 0, stream>>>(stgE, stgV, cursE, cursV, eoffs, voffs, ecsr, vcsr);
  edge_agg<<<(E + 15)/16, 256, 0, stream>>>(X0bf, att, ecsr, eoffs, gmaxU, Xe8, alphaS, E);
  vert_pass<<<(N + 15)/16, 256, 0, stream>>>(X0bf, Xe8, alphaS, gmaxU, vcsr, voffs, (float*)d_out, N);
}